// Round 3
// baseline (145.700 us; speedup 1.0000x reference)
//
#include <hip/hip_runtime.h>

// Problem constants: B=4, T=1024, F=500, H=128, P=64
// All external buffers fp32 (per reference dtypes). Internal GEMMs in bf16.
// out = [probs (B*T*P=262144), all_states (T*B*H=524288)] fp32
//
// ws layout (8 MB total):
//   gi_bf    [0,        3145728)  4096*384 bf16
//   S_bf     [3145728,  4194304)  4096*128 bf16   (states, [T,B,H])
//   Wc       [4194304,  6291456)  64*128*128 bf16 (folded ctx weights)
//   gate_pre [6291456,  8388608)  4096*128 fp32   (atomic split-K accumulator)

typedef short bf16x8 __attribute__((ext_vector_type(8)));
typedef float f32x4 __attribute__((ext_vector_type(4)));
typedef unsigned short u16;
typedef unsigned int u32;

__device__ __forceinline__ float bf2f(u16 u) {
  union { u32 i; float f; } v; v.i = ((u32)u) << 16; return v.f;
}
__device__ __forceinline__ u16 f2bf(float f) {
  union { float f; u32 i; } v; v.f = f;
  u32 u = v.i;
  return (u16)((u + 0x7FFFu + ((u >> 16) & 1u)) >> 16);
}
__device__ __forceinline__ float sigmoidf_(float x) {
  return 1.0f / (1.0f + __expf(-x));
}

#define NWC (64*128*128)
#define NZ  (131072)   // 524288 floats / 4 (float4 zero-fill of gate_pre)

// Wc[p][h'][h] = W_ctx[h', (128+h)*64+p]; part1 row-collapse
// W1[h',h] = sum_q W_ctx[h', h*64+q] folded into p==0 (s[clip(t-0)] = s[t]).
// Also zero gate_pre for the atomic split-K accumulation.
__global__ void k_prep(const float* __restrict__ W_ctx,
                       u16* __restrict__ Wc, float* __restrict__ gate_pre) {
  int g = blockIdx.x * 256 + threadIdx.x;
  if (g < NWC) {
    int p = g >> 14;
    int rem = g & 16383;
    int hp = rem >> 7;   // h' (output gate channel)
    int h = rem & 127;   // input state channel
    const float* wrow = W_ctx + hp * 16384;
    float val = wrow[8192 + h * 64 + p];
    if (p == 0) {
      float s = 0.f;
      for (int q = 0; q < 64; ++q) s += wrow[h * 64 + q];
      val += s;
    }
    Wc[g] = f2bf(val);
  } else if (g < NWC + NZ) {
    int g2 = g - NWC;
    ((float4*)gate_pre)[g2] = make_float4(0.f, 0.f, 0.f, 0.f);
  }
}

// gi = x @ W_ih^T  (M=4096, N=384, K=500 padded to 512 in LDS), bf16 out.
// fp32 inputs staged with float4 loads (row stride 2000 B = 16B-aligned),
// converted to bf16 on LDS write. K-tail (500..511) zero-filled.
__global__ __launch_bounds__(256) void k_gemm_gi(const float* __restrict__ x,
                                                 const float* __restrict__ W_ih,
                                                 u16* __restrict__ gi_bf) {
  __shared__ u16 Asm[64][136];   // +8 pad
  __shared__ u16 Bsm[128][136];
  const int tid = threadIdx.x;
  const int r0 = blockIdx.x * 64;
  const int n0 = blockIdx.y * 128;
  const int lane = tid & 63, wave = tid >> 6;
  const int l15 = lane & 15, quad = lane >> 4;
  f32x4 acc[4][2];
  for (int i = 0; i < 4; ++i)
    for (int j = 0; j < 2; ++j) acc[i][j] = (f32x4){0.f, 0.f, 0.f, 0.f};

  for (int kb = 0; kb < 4; ++kb) {
    const int kg = kb * 128;
    const int kcols = (kb == 3) ? 29 : 32;   // valid float4 columns (tail: 116)
    __syncthreads();
    for (int rr = 0; rr < 8; ++rr) {         // A: 64 rows x 32 float4
      int i = rr * 256 + tid;
      int m = i >> 5, cu = i & 31;
      float4 v = make_float4(0.f, 0.f, 0.f, 0.f);
      if (cu < kcols) v = *(const float4*)(x + (size_t)(r0 + m) * 500 + kg + cu * 4);
      u16* dst = &Asm[m][cu * 4];
      dst[0] = f2bf(v.x); dst[1] = f2bf(v.y); dst[2] = f2bf(v.z); dst[3] = f2bf(v.w);
    }
    for (int rr = 0; rr < 16; ++rr) {        // B: 128 rows x 32 float4
      int i = rr * 256 + tid;
      int n = i >> 5, cu = i & 31;
      float4 v = make_float4(0.f, 0.f, 0.f, 0.f);
      if (cu < kcols) v = *(const float4*)(W_ih + (size_t)(n0 + n) * 500 + kg + cu * 4);
      u16* dst = &Bsm[n][cu * 4];
      dst[0] = f2bf(v.x); dst[1] = f2bf(v.y); dst[2] = f2bf(v.z); dst[3] = f2bf(v.w);
    }
    __syncthreads();
    for (int kk = 0; kk < 4; ++kk) {
      int kbase = kk * 32 + quad * 8;
      bf16x8 b0 = *(const bf16x8*)&Bsm[wave * 32 + l15][kbase];
      bf16x8 b1 = *(const bf16x8*)&Bsm[wave * 32 + 16 + l15][kbase];
      for (int mt = 0; mt < 4; ++mt) {
        bf16x8 a = *(const bf16x8*)&Asm[mt * 16 + l15][kbase];
        acc[mt][0] = __builtin_amdgcn_mfma_f32_16x16x32_bf16(a, b0, acc[mt][0], 0, 0, 0);
        acc[mt][1] = __builtin_amdgcn_mfma_f32_16x16x32_bf16(a, b1, acc[mt][1], 0, 0, 0);
      }
    }
  }
  for (int mt = 0; mt < 4; ++mt)
    for (int nt = 0; nt < 2; ++nt)
      for (int rg = 0; rg < 4; ++rg) {
        int m = r0 + mt * 16 + quad * 4 + rg;       // C/D: row=(lane>>4)*4+reg
        int n = n0 + wave * 32 + nt * 16 + l15;     //      col=lane&15
        gi_bf[m * 384 + n] = f2bf(acc[mt][nt][rg]);
      }
}

// GRU gates with h=0: r=sig(gr+br), z=sig(gz+bz), n=tanh(gn + r*bn), s=(1-z)*n.
// Writes S_bf (bf16, ws) and the fp32 all_states output.
__global__ void k_states(const u16* __restrict__ gi_bf,
                         const float* __restrict__ b_ih, const float* __restrict__ b_hh,
                         u16* __restrict__ S_bf, float* __restrict__ out_states) {
  int g = blockIdx.x * 256 + threadIdx.x;  // 4096*128
  int r = g >> 7, h = g & 127;
  float xr = bf2f(gi_bf[r * 384 + h])       + b_ih[h]       + b_hh[h];
  float xz = bf2f(gi_bf[r * 384 + 128 + h]) + b_ih[128 + h] + b_hh[128 + h];
  float xn = bf2f(gi_bf[r * 384 + 256 + h]) + b_ih[256 + h];
  float rg = sigmoidf_(xr);
  float zg = sigmoidf_(xz);
  float n = tanhf(xn + rg * b_hh[256 + h]);
  float s = (1.f - zg) * n;
  int b = r >> 10, t = r & 1023;   // gi rows are (b,t); state rows are (t,b)
  S_bf[(t * 4 + b) * 128 + h] = f2bf(s);
  out_states[(t * 4 + b) * 128 + h] = s;
}

// Context gate GEMM, split-K over p: gate_pre[t,b,:] += Wc_p @ s[max(t-p,0),b].
// A-tile at K-block p is S_bf shifted by 4p rows (clamped at 0).
// Grid (64 M-tiles, 8 K-chunks); fp32 atomicAdd into gate_pre (zeroed by k_prep).
__global__ __launch_bounds__(256) void k_gemm_ctx(const u16* __restrict__ S_bf,
                                                  const u16* __restrict__ Wc,
                                                  float* __restrict__ gate_pre) {
  __shared__ u16 Asm[64][136];
  __shared__ u16 Bsm[128][136];
  const int tid = threadIdx.x;
  const int r0 = blockIdx.x * 64;
  const int chunk = blockIdx.y;  // p in [chunk*8, chunk*8+8)
  const int lane = tid & 63, wave = tid >> 6;
  const int l15 = lane & 15, quad = lane >> 4;
  f32x4 acc[4][2];
  for (int i = 0; i < 4; ++i)
    for (int j = 0; j < 2; ++j) acc[i][j] = (f32x4){0.f, 0.f, 0.f, 0.f};

  for (int pi = 0; pi < 8; ++pi) {
    int p = chunk * 8 + pi;
    __syncthreads();
    for (int rr = 0; rr < 4; ++rr) {
      int e = (rr * 256 + tid) * 8;
      int m = e >> 7, c = e & 127;
      int r = r0 + m;
      int t = r >> 2, b = r & 3;
      int ts = t - p; if (ts < 0) ts = 0;   // clip(t-p, 0)
      *(uint4*)&Asm[m][c] = *(const uint4*)(S_bf + (ts * 4 + b) * 128 + c);
    }
    const u16* Wp = Wc + p * 16384;
    for (int rr = 0; rr < 8; ++rr) {
      int e = (rr * 256 + tid) * 8;
      int n = e >> 7, c = e & 127;
      *(uint4*)&Bsm[n][c] = *(const uint4*)(Wp + n * 128 + c);
    }
    __syncthreads();
    for (int kk = 0; kk < 4; ++kk) {
      int kbase = kk * 32 + quad * 8;
      bf16x8 b0 = *(const bf16x8*)&Bsm[wave * 32 + l15][kbase];
      bf16x8 b1 = *(const bf16x8*)&Bsm[wave * 32 + 16 + l15][kbase];
      for (int mt = 0; mt < 4; ++mt) {
        bf16x8 a = *(const bf16x8*)&Asm[mt * 16 + l15][kbase];
        acc[mt][0] = __builtin_amdgcn_mfma_f32_16x16x32_bf16(a, b0, acc[mt][0], 0, 0, 0);
        acc[mt][1] = __builtin_amdgcn_mfma_f32_16x16x32_bf16(a, b1, acc[mt][1], 0, 0, 0);
      }
    }
  }
  for (int mt = 0; mt < 4; ++mt)
    for (int nt = 0; nt < 2; ++nt)
      for (int rg = 0; rg < 4; ++rg) {
        int m = r0 + mt * 16 + quad * 4 + rg;
        int n = wave * 32 + nt * 16 + l15;
        atomicAdd(&gate_pre[m * 128 + n], acc[mt][nt][rg]);
      }
}

// gate = sigmoid(gate_pre + b_ctx); gated = states*gate; probs = clip(sig(FC)).
__global__ __launch_bounds__(256) void k_epilogue(const float* __restrict__ gate_pre,
                                                  const u16* __restrict__ S_bf,
                                                  const float* __restrict__ b_ctx,
                                                  const float* __restrict__ W_fc,
                                                  const float* __restrict__ b_fc,
                                                  float* __restrict__ out_probs) {
  __shared__ float Wfc[64][129];   // +1 pad
  __shared__ float gated[16][128];
  const int tid = threadIdx.x;
  const int row0 = blockIdx.x * 16;
  for (int i = tid; i < 64 * 128; i += 256)
    Wfc[i >> 7][i & 127] = W_fc[i];
  for (int it = 0; it < 8; ++it) {
    int lr = it * 2 + (tid >> 7);
    int h = tid & 127;
    int sr = row0 + lr;
    float gp = gate_pre[sr * 128 + h] + b_ctx[h];
    float gate = sigmoidf_(gp);
    gated[lr][h] = bf2f(S_bf[sr * 128 + h]) * gate;
  }
  __syncthreads();
  for (int it = 0; it < 4; ++it) {
    int o = it * 256 + tid;
    int lr = o >> 6, pp = o & 63;
    int sr = row0 + lr;
    const float* gr = gated[lr];
    const float* wr = Wfc[pp];
    float dot = 0.f;
#pragma unroll
    for (int h = 0; h < 128; ++h) dot += gr[h] * wr[h];
    float pv = sigmoidf_(dot + b_fc[pp]);
    pv = (pv > 0.001f) ? pv : 0.001f;   // NaN-proof clamp ordering
    pv = (pv < 0.999f) ? pv : 0.999f;
    int t = sr >> 2, b = sr & 3;
    out_probs[(b * 1024 + t) * 64 + pp] = pv;
  }
}

extern "C" void kernel_launch(void* const* d_in, const int* in_sizes, int n_in,
                              void* d_out, int out_size, void* d_ws, size_t ws_size,
                              hipStream_t stream) {
  const float* x     = (const float*)d_in[0];
  const float* W_ih  = (const float*)d_in[1];
  // d_in[2] = W_hh: unused (hidden state is always 0 in the reference)
  const float* b_ih  = (const float*)d_in[3];
  const float* b_hh  = (const float*)d_in[4];
  const float* W_ctx = (const float*)d_in[5];
  const float* b_ctx = (const float*)d_in[6];
  const float* W_fc  = (const float*)d_in[7];
  const float* b_fc  = (const float*)d_in[8];
  float* out = (float*)d_out;

  char* ws = (char*)d_ws;
  u16*   gi_bf    = (u16*)  (ws + 0);          // 3,145,728 B
  u16*   S_bf     = (u16*)  (ws + 3145728);    // 1,048,576 B
  u16*   Wc       = (u16*)  (ws + 4194304);    // 2,097,152 B
  float* gate_pre = (float*)(ws + 6291456);    // 2,097,152 B
  // total ws used: 8,388,608 bytes (8 MB)

  k_prep<<<4608, 256, 0, stream>>>(W_ctx, Wc, gate_pre);
  k_gemm_gi<<<dim3(64, 3), 256, 0, stream>>>(x, W_ih, gi_bf);
  k_states<<<2048, 256, 0, stream>>>(gi_bf, b_ih, b_hh, S_bf, out + 262144);
  k_gemm_ctx<<<dim3(64, 8), 256, 0, stream>>>(S_bf, Wc, gate_pre);
  k_epilogue<<<256, 256, 0, stream>>>(gate_pre, S_bf, b_ctx, W_fc, b_fc, out);
}